// Round 1
// baseline (132.584 us; speedup 1.0000x reference)
//
#include <hip/hip_runtime.h>
#include <cstdint>
#include <cstddef>

typedef __attribute__((ext_vector_type(4))) float  f32x4;
typedef __attribute__((ext_vector_type(8))) short  short8;
typedef __attribute__((ext_vector_type(4))) short  short4v;

__device__ __forceinline__ short f2bf(float f) {
  unsigned u = __float_as_uint(f);
  u += 0x7FFF + ((u >> 16) & 1);   // round-to-nearest-even
  return (short)(u >> 16);
}
__device__ __forceinline__ float sigmoidf(float x) {
  return 1.0f / (1.0f + __expf(-x));
}

// ---------------- pool: g[b,c] = mean_s x[b,c,s], one wave per row ----------
__global__ __launch_bounds__(256) void pool_kernel(const float* __restrict__ x,
                                                   float* __restrict__ g,
                                                   int nrows) {
  int gid  = blockIdx.x * 256 + threadIdx.x;
  int row  = gid >> 6;
  int lane = threadIdx.x & 63;
  if (row >= nrows) return;
  float s = 0.f;
  if (lane < 49) {                       // 196 floats = 49 float4
    const float4* p = (const float4*)(x + (size_t)row * 196);
    float4 v = p[lane];
    s = v.x + v.y + v.z + v.w;
  }
#pragma unroll
  for (int off = 32; off > 0; off >>= 1) s += __shfl_down(s, off);
  if (lane == 0) g[row] = s * (1.0f / 196.0f);
}

// --------- GEMM (BT layout, M=64) with K-split, bf16 MFMA, f32 partials -----
// out_part[ks][m][n] = sum_{k in chunk ks} A[m,k] * B[n,k]
template<int N, int K, int KCHUNK>
__global__ __launch_bounds__(256) void gemm_bt_part(const float* __restrict__ A,
                                                    const float* __restrict__ B,
                                                    float* __restrict__ part) {
  constexpr int BM = 64, BN = 128, BK = 64;
  constexpr int NT = N / BN;
  const int nt = blockIdx.x % NT;
  const int ks = blockIdx.x / NT;
  const int n0 = nt * BN;
  const int k0 = ks * KCHUNK;

  __shared__ short As[BM * BK];   // bf16, XOR-swizzled rows of 128B
  __shared__ short Bs[BN * BK];

  const int tid  = threadIdx.x;
  const int lane = tid & 63;
  const int wv   = tid >> 6;
  const int wm   = wv >> 1, wn = wv & 1;   // 2x2 wave grid, each 32x64

  f32x4 acc[2][4] = {};

  for (int t = 0; t < KCHUNK / BK; ++t) {
    const int kt = k0 + t * BK;
    __syncthreads();
    // stage A: 64x64 f32 -> bf16 (1024 float4, 4/thread)
#pragma unroll
    for (int i = 0; i < 4; ++i) {
      int f = i * 256 + tid;
      int row = f >> 4, c4 = f & 15;
      float4 v = *(const float4*)(A + (size_t)row * K + kt + c4 * 4);
      short4v sv; sv.x = f2bf(v.x); sv.y = f2bf(v.y); sv.z = f2bf(v.z); sv.w = f2bf(v.w);
      int bo = (c4 * 8) ^ ((row & 7) << 4);
      *(short4v*)(As + row * 64 + (bo >> 1)) = sv;
    }
    // stage B: 128x64 f32 -> bf16 (2048 float4, 8/thread)
#pragma unroll
    for (int i = 0; i < 8; ++i) {
      int f = i * 256 + tid;
      int row = f >> 4, c4 = f & 15;
      float4 v = *(const float4*)(B + (size_t)(n0 + row) * K + kt + c4 * 4);
      short4v sv; sv.x = f2bf(v.x); sv.y = f2bf(v.y); sv.z = f2bf(v.z); sv.w = f2bf(v.w);
      int bo = (c4 * 8) ^ ((row & 7) << 4);
      *(short4v*)(Bs + row * 64 + (bo >> 1)) = sv;
    }
    __syncthreads();
#pragma unroll
    for (int kk = 0; kk < 2; ++kk) {
      const int kbyte = kk * 64 + ((lane >> 4) << 4);
      short8 af[2], bf[4];
#pragma unroll
      for (int mi = 0; mi < 2; ++mi) {
        int row = wm * 32 + mi * 16 + (lane & 15);
        int bo  = kbyte ^ ((row & 7) << 4);
        af[mi]  = *(const short8*)(As + row * 64 + (bo >> 1));
      }
#pragma unroll
      for (int ni = 0; ni < 4; ++ni) {
        int row = wn * 64 + ni * 16 + (lane & 15);
        int bo  = kbyte ^ ((row & 7) << 4);
        bf[ni]  = *(const short8*)(Bs + row * 64 + (bo >> 1));
      }
#pragma unroll
      for (int mi = 0; mi < 2; ++mi)
#pragma unroll
        for (int ni = 0; ni < 4; ++ni)
          acc[mi][ni] = __builtin_amdgcn_mfma_f32_16x16x32_bf16(af[mi], bf[ni], acc[mi][ni], 0, 0, 0);
    }
  }
  // write f32 partial tile (C/D layout: row=(lane>>4)*4+r, col=lane&15)
  float* pp = part + (size_t)ks * BM * N;
#pragma unroll
  for (int mi = 0; mi < 2; ++mi)
#pragma unroll
    for (int ni = 0; ni < 4; ++ni)
#pragma unroll
      for (int r = 0; r < 4; ++r) {
        int m = wm * 32 + mi * 16 + ((lane >> 4) << 2) + r;
        int n = n0 + wn * 64 + ni * 16 + (lane & 15);
        pp[(size_t)m * N + n] = acc[mi][ni][r];
      }
}

// --------- reduce K-split partials + bias + sigmoid -------------------------
template<int KS>
__global__ __launch_bounds__(256) void bias_sigmoid_reduce(const float* __restrict__ part,
                                                           const float* __restrict__ bias,
                                                           float* __restrict__ out,
                                                           int MN, int N) {
  int i = blockIdx.x * 256 + threadIdx.x;
  int e = i * 4;
  if (e >= MN) return;
  float4 s = {0.f, 0.f, 0.f, 0.f};
#pragma unroll
  for (int k = 0; k < KS; ++k) {
    float4 v = *(const float4*)(part + (size_t)k * MN + e);
    s.x += v.x; s.y += v.y; s.z += v.z; s.w += v.w;
  }
  float4 b = *(const float4*)(bias + (e % N));
  s.x = sigmoidf(s.x + b.x);
  s.y = sigmoidf(s.y + b.y);
  s.z = sigmoidf(s.z + b.z);
  s.w = sigmoidf(s.w + b.w);
  *(float4*)(out + e) = s;
}

// --------- einsum: feat[b,p,s] = (1/C) sum_c w[b,p,c] * x[b,c,s] ------------
// grid = 64 batches x 4 c-chunks of 512; atomicAdd into zeroed feat
__global__ __launch_bounds__(256) void einsum_kernel(const float* __restrict__ x,
                                                     const float* __restrict__ wg,
                                                     float* __restrict__ feat) {
  const int b  = blockIdx.x >> 2;
  const int cc = blockIdx.x & 3;
  __shared__ float gs[2048];              // w[b, p=0..3, c-chunk of 512]
  const int tid = threadIdx.x;
  const float* wb = wg + (size_t)b * 8192;
#pragma unroll
  for (int i = 0; i < 8; ++i) {
    int idx = i * 256 + tid;              // p*512 + c
    int p = idx >> 9, c = idx & 511;
    gs[idx] = wb[p * 2048 + cc * 512 + c];
  }
  __syncthreads();
  if (tid < 196) {
    const float* xp = x + (size_t)b * 2048 * 196 + (size_t)cc * 512 * 196 + tid;
    float a0 = 0, a1 = 0, a2 = 0, a3 = 0;
#pragma unroll 4
    for (int c = 0; c < 512; ++c) {
      float xv = xp[(size_t)c * 196];
      a0 += gs[c]        * xv;
      a1 += gs[512  + c] * xv;
      a2 += gs[1024 + c] * xv;
      a3 += gs[1536 + c] * xv;
    }
    const float invC = 1.0f / 2048.0f;
    atomicAdd(feat + (b * 4 + 0) * 196 + tid, a0 * invC);
    atomicAdd(feat + (b * 4 + 1) * 196 + tid, a1 * invC);
    atomicAdd(feat + (b * 4 + 2) * 196 + tid, a2 * invC);
    atomicAdd(feat + (b * 4 + 3) * 196 + tid, a3 * invC);
  }
}

extern "C" void kernel_launch(void* const* d_in, const int* in_sizes, int n_in,
                              void* d_out, int out_size, void* d_ws, size_t ws_size,
                              hipStream_t stream) {
  const float* x  = (const float*)d_in[0];   // [64,2048,14,14]
  const float* w1 = (const float*)d_in[1];   // [4096,2048]
  const float* b1 = (const float*)d_in[2];   // [4096]
  const float* w2 = (const float*)d_in[3];   // [8192,4096]
  const float* b2 = (const float*)d_in[4];   // [8192]
  float* out = (float*)d_out;

  float* g    = (float*)d_ws;                // 64*2048
  float* h    = g + 64 * 2048;               // 64*4096
  float* part = h + 64 * 4096;               // 2,097,152 floats (shared by both GEMMs)

  float* wout = out;                         // [64, 8192] == [B,P,C] flat
  float* feat = out + 524288;                // [64, 4, 196]

  hipMemsetAsync(feat, 0, 50176 * sizeof(float), stream);

  // 1) pool
  pool_kernel<<<(64 * 2048) / 4, 256, 0, stream>>>(x, g, 64 * 2048);

  // 2) GEMM1: h = sigmoid(g @ w1^T + b1)   (N=4096, K=2048, 8-way K-split)
  gemm_bt_part<4096, 2048, 256><<<(4096 / 128) * 8, 256, 0, stream>>>(g, w1, part);
  bias_sigmoid_reduce<8><<<(64 * 4096 / 4) / 256, 256, 0, stream>>>(part, b1, h, 64 * 4096, 4096);

  // 3) GEMM2: w = sigmoid(h @ w2^T + b2)   (N=8192, K=4096, 4-way K-split)
  gemm_bt_part<8192, 4096, 1024><<<(8192 / 128) * 4, 256, 0, stream>>>(h, w2, part);
  bias_sigmoid_reduce<4><<<(64 * 8192 / 4) / 256, 256, 0, stream>>>(part, b2, wout, 64 * 8192, 8192);

  // 4) einsum feat = w @ xs / C
  einsum_kernel<<<64 * 4, 256, 0, stream>>>(x, wout, feat);
}

// Round 2
// 107.224 us; speedup vs baseline: 1.2365x; 1.2365x over previous
//
#include <hip/hip_runtime.h>
#include <cstdint>
#include <cstddef>

typedef __attribute__((ext_vector_type(4))) float  f32x4;
typedef __attribute__((ext_vector_type(8))) short  short8;
typedef __attribute__((ext_vector_type(4))) short  short4v;

__device__ __forceinline__ short f2bf(float f) {
  unsigned u = __float_as_uint(f);
  u += 0x7FFF + ((u >> 16) & 1);   // round-to-nearest-even
  return (short)(u >> 16);
}
__device__ __forceinline__ float sigmoidf(float x) {
  return 1.0f / (1.0f + __expf(-x));
}

// ---------------- pool: g[b,c] = mean_s x[b,c,s], one wave per row ----------
__global__ __launch_bounds__(256) void pool_kernel(const float* __restrict__ x,
                                                   float* __restrict__ g,
                                                   int nrows) {
  int gid  = blockIdx.x * 256 + threadIdx.x;
  int row  = gid >> 6;
  int lane = threadIdx.x & 63;
  if (row >= nrows) return;
  float s = 0.f;
  if (lane < 49) {                       // 196 floats = 49 float4
    const float4* p = (const float4*)(x + (size_t)row * 196);
    float4 v = p[lane];
    s = v.x + v.y + v.z + v.w;
  }
#pragma unroll
  for (int off = 32; off > 0; off >>= 1) s += __shfl_down(s, off);
  if (lane == 0) g[row] = s * (1.0f / 196.0f);
}

// --------- GEMM (BT layout, M=64) with K-split, bf16 MFMA, f32 partials -----
// out_part[ks][m][n] = sum_{k in chunk ks} A[m,k] * B[n,k]
template<int N, int K, int KCHUNK>
__global__ __launch_bounds__(256) void gemm_bt_part(const float* __restrict__ A,
                                                    const float* __restrict__ B,
                                                    float* __restrict__ part) {
  constexpr int BM = 64, BN = 128, BK = 64;
  constexpr int NT = N / BN;
  const int nt = blockIdx.x % NT;
  const int ks = blockIdx.x / NT;
  const int n0 = nt * BN;
  const int k0 = ks * KCHUNK;

  __shared__ short As[BM * BK];   // bf16, XOR-swizzled rows of 128B
  __shared__ short Bs[BN * BK];

  const int tid  = threadIdx.x;
  const int lane = tid & 63;
  const int wv   = tid >> 6;
  const int wm   = wv >> 1, wn = wv & 1;   // 2x2 wave grid, each 32x64

  f32x4 acc[2][4] = {};

  for (int t = 0; t < KCHUNK / BK; ++t) {
    const int kt = k0 + t * BK;
    __syncthreads();
    // stage A: 64x64 f32 -> bf16 (1024 float4, 4/thread)
#pragma unroll
    for (int i = 0; i < 4; ++i) {
      int f = i * 256 + tid;
      int row = f >> 4, c4 = f & 15;
      float4 v = *(const float4*)(A + (size_t)row * K + kt + c4 * 4);
      short4v sv; sv.x = f2bf(v.x); sv.y = f2bf(v.y); sv.z = f2bf(v.z); sv.w = f2bf(v.w);
      int bo = (c4 * 8) ^ ((row & 7) << 4);
      *(short4v*)(As + row * 64 + (bo >> 1)) = sv;
    }
    // stage B: 128x64 f32 -> bf16 (2048 float4, 8/thread)
#pragma unroll
    for (int i = 0; i < 8; ++i) {
      int f = i * 256 + tid;
      int row = f >> 4, c4 = f & 15;
      float4 v = *(const float4*)(B + (size_t)(n0 + row) * K + kt + c4 * 4);
      short4v sv; sv.x = f2bf(v.x); sv.y = f2bf(v.y); sv.z = f2bf(v.z); sv.w = f2bf(v.w);
      int bo = (c4 * 8) ^ ((row & 7) << 4);
      *(short4v*)(Bs + row * 64 + (bo >> 1)) = sv;
    }
    __syncthreads();
#pragma unroll
    for (int kk = 0; kk < 2; ++kk) {
      const int kbyte = kk * 64 + ((lane >> 4) << 4);
      short8 af[2], bf[4];
#pragma unroll
      for (int mi = 0; mi < 2; ++mi) {
        int row = wm * 32 + mi * 16 + (lane & 15);
        int bo  = kbyte ^ ((row & 7) << 4);
        af[mi]  = *(const short8*)(As + row * 64 + (bo >> 1));
      }
#pragma unroll
      for (int ni = 0; ni < 4; ++ni) {
        int row = wn * 64 + ni * 16 + (lane & 15);
        int bo  = kbyte ^ ((row & 7) << 4);
        bf[ni]  = *(const short8*)(Bs + row * 64 + (bo >> 1));
      }
#pragma unroll
      for (int mi = 0; mi < 2; ++mi)
#pragma unroll
        for (int ni = 0; ni < 4; ++ni)
          acc[mi][ni] = __builtin_amdgcn_mfma_f32_16x16x32_bf16(af[mi], bf[ni], acc[mi][ni], 0, 0, 0);
    }
  }
  // write f32 partial tile (C/D layout: row=(lane>>4)*4+r, col=lane&15)
  float* pp = part + (size_t)ks * BM * N;
#pragma unroll
  for (int mi = 0; mi < 2; ++mi)
#pragma unroll
    for (int ni = 0; ni < 4; ++ni)
#pragma unroll
      for (int r = 0; r < 4; ++r) {
        int m = wm * 32 + mi * 16 + ((lane >> 4) << 2) + r;
        int n = n0 + wn * 64 + ni * 16 + (lane & 15);
        pp[(size_t)m * N + n] = acc[mi][ni][r];
      }
}

// --------- reduce K-split partials + bias + sigmoid -------------------------
template<int KS>
__global__ __launch_bounds__(256) void bias_sigmoid_reduce(const float* __restrict__ part,
                                                           const float* __restrict__ bias,
                                                           float* __restrict__ out,
                                                           int MN, int N) {
  int i = blockIdx.x * 256 + threadIdx.x;
  int e = i * 4;
  if (e >= MN) return;
  float4 s = {0.f, 0.f, 0.f, 0.f};
#pragma unroll
  for (int k = 0; k < KS; ++k) {
    float4 v = *(const float4*)(part + (size_t)k * MN + e);
    s.x += v.x; s.y += v.y; s.z += v.z; s.w += v.w;
  }
  float4 b = *(const float4*)(bias + (e % N));
  s.x = sigmoidf(s.x + b.x);
  s.y = sigmoidf(s.y + b.y);
  s.z = sigmoidf(s.z + b.z);
  s.w = sigmoidf(s.w + b.w);
  *(float4*)(out + e) = s;
}

// --------- einsum partials: fpart[(b*8+cc)*4+p][s] = sum_{c in chunk} w*x ---
// grid = 64 batches x 8 c-chunks of 256; no atomics, no memset
__global__ __launch_bounds__(256) void einsum_part(const float* __restrict__ x,
                                                   const float* __restrict__ wg,
                                                   float* __restrict__ fpart) {
  const int b  = blockIdx.x >> 3;
  const int cc = blockIdx.x & 7;
  __shared__ float gs[4 * 256];           // w[b, p=0..3, c-chunk of 256]
  const int tid = threadIdx.x;
  const float* wb = wg + (size_t)b * 8192 + cc * 256;
#pragma unroll
  for (int i = 0; i < 4; ++i) {
    int idx = i * 256 + tid;              // p*256 + c
    int p = idx >> 8, c = idx & 255;
    gs[idx] = wb[p * 2048 + c];
  }
  __syncthreads();
  if (tid < 196) {
    const float* xp = x + (size_t)b * 2048 * 196 + (size_t)cc * 256 * 196 + tid;
    float a0 = 0, a1 = 0, a2 = 0, a3 = 0;
#pragma unroll 8
    for (int c = 0; c < 256; ++c) {
      float xv = xp[(size_t)c * 196];
      a0 += gs[c]        * xv;
      a1 += gs[256  + c] * xv;
      a2 += gs[512  + c] * xv;
      a3 += gs[768  + c] * xv;
    }
    float* fp = fpart + ((size_t)(b * 8 + cc) * 4) * 196 + tid;
    fp[0]   = a0;
    fp[196] = a1;
    fp[392] = a2;
    fp[588] = a3;
  }
}

// --------- reduce einsum c-chunk partials, scale by 1/C ---------------------
__global__ __launch_bounds__(256) void feat_reduce(const float* __restrict__ fpart,
                                                   float* __restrict__ feat) {
  int i = blockIdx.x * 256 + threadIdx.x;   // 64*4*196 = 50176 elems
  if (i >= 64 * 4 * 196) return;
  int s = i % 196;
  int p = (i / 196) & 3;
  int b = i / 784;
  float sum = 0.f;
#pragma unroll
  for (int cc = 0; cc < 8; ++cc)
    sum += fpart[((size_t)(b * 8 + cc) * 4 + p) * 196 + s];
  feat[i] = sum * (1.0f / 2048.0f);
}

extern "C" void kernel_launch(void* const* d_in, const int* in_sizes, int n_in,
                              void* d_out, int out_size, void* d_ws, size_t ws_size,
                              hipStream_t stream) {
  const float* x  = (const float*)d_in[0];   // [64,2048,14,14]
  const float* w1 = (const float*)d_in[1];   // [4096,2048]
  const float* b1 = (const float*)d_in[2];   // [4096]
  const float* w2 = (const float*)d_in[3];   // [8192,4096]
  const float* b2 = (const float*)d_in[4];   // [8192]
  float* out = (float*)d_out;

  float* g     = (float*)d_ws;               // 64*2048
  float* h     = g + 64 * 2048;              // 64*4096
  float* part  = h + 64 * 4096;              // 16 * 64*8192 = 8,388,608 floats max
  float* fpart = part + 16 * 64 * 8192;      // 64*8*4*196 = 401,408 floats

  float* wout = out;                         // [64, 8192] == [B,P,C] flat
  float* feat = out + 524288;                // [64, 4, 196]

  // 1) pool
  pool_kernel<<<(64 * 2048) / 4, 256, 0, stream>>>(x, g, 64 * 2048);

  // 2) GEMM1: h = sigmoid(g @ w1^T + b1)   (N=4096, K=2048, 16-way K-split)
  gemm_bt_part<4096, 2048, 128><<<(4096 / 128) * 16, 256, 0, stream>>>(g, w1, part);
  bias_sigmoid_reduce<16><<<(64 * 4096 / 4) / 256, 256, 0, stream>>>(part, b1, h, 64 * 4096, 4096);

  // 3) GEMM2: w = sigmoid(h @ w2^T + b2)   (N=8192, K=4096, 16-way K-split)
  gemm_bt_part<8192, 4096, 256><<<(8192 / 128) * 16, 256, 0, stream>>>(h, w2, part);
  bias_sigmoid_reduce<16><<<(64 * 8192 / 4) / 256, 256, 0, stream>>>(part, b2, wout, 64 * 8192, 8192);

  // 4) einsum feat = w @ xs / C  (8-way c-split partials + reduce)
  einsum_part<<<64 * 8, 256, 0, stream>>>(x, wout, fpart);
  feat_reduce<<<(50176 + 255) / 256, 256, 0, stream>>>(fpart, feat);
}